// Round 18
// baseline (136.822 us; speedup 1.0000x reference)
//
#include <hip/hip_runtime.h>
#include <hip/hip_bf16.h>
#include <hip/hip_fp8.h>

#define B_SZ 8192
#define D_SZ 256          // elements per row; fp8 row = 256 B
#define NTILES 2080       // (8192/128)*(8192/128+1)/2 upper-tri tiles
#define GRID_SIM 1024     // persistent, 4 blocks/CU (32 KB LDS, ~112 VGPR)
// rows pre-scaled by sqrt(log2(e)/T): exp2(acc) == exp(sim/T)
#define PRESCALE 4.539816004686735f

typedef __attribute__((ext_vector_type(4))) float f32x4;

// ---------------- L2-normalize rows, scale, cast to FP8 e4m3 (+ zero sums) -
__global__ __launch_bounds__(256) void norm_kernel(const float* __restrict__ emb,
                                                   unsigned char* __restrict__ nq,
                                                   float* __restrict__ sums) {
    // zero all_sum+pos_sum: 16384 floats over 256 blocks
    sums[blockIdx.x * 64 + (threadIdx.x >> 2)] = 0.0f;

    const int wave = threadIdx.x >> 6, lane = threadIdx.x & 63;
    for (int g = blockIdx.x; g < B_SZ / 4; g += 256) {
        const int row = g * 4 + wave;
        const float4 v = ((const float4*)(emb + (size_t)row * D_SZ))[lane];
        float ss = v.x * v.x + v.y * v.y + v.z * v.z + v.w * v.w;
        #pragma unroll
        for (int m = 1; m < 64; m <<= 1) ss += __shfl_xor(ss, m, 64);
        float s = PRESCALE / fmaxf(sqrtf(ss), 1e-12f);
        __hip_fp8_e4m3 q0(v.x * s), q1(v.y * s), q2(v.z * s), q3(v.w * s);
        uchar4 o;
        o.x = q0.__x; o.y = q1.__x; o.z = q2.__x; o.w = q3.__x;
        ((uchar4*)(nq + (size_t)row * D_SZ))[lane] = o;
    }
}

// ---------------- helpers ---------------------------------------------------
__device__ __forceinline__ void decode_tile(int tb, int& i0, int& j0, bool& diag) {
    int bj = (int)((sqrtf(8.0f * tb + 1.0f) - 1.0f) * 0.5f);
    while ((bj + 1) * (bj + 2) / 2 <= tb) ++bj;
    while (bj * (bj + 1) / 2 > tb) --bj;
    const int bi = tb - bj * (bj + 1) / 2;
    i0 = bi * 128; j0 = bj * 128; diag = (bi == bj);
}

// global -> VGPR staging, fp8 (exact vmcnt tracking; loads cross barriers).
// r13 layout: lane covers row rl = wave*32 + h*16 + (lane>>2), 16B slot
// lane&3; source chunk16 XOR-swizzled by (rl>>1)&3.
__device__ __forceinline__ void load_regs(int4 ra[2], int4 rb[2],
                                          const unsigned char* __restrict__ N,
                                          int i0, int j0, int k0,
                                          int wave, int lane) {
    const int rowIn = lane >> 2, slot = lane & 3;
    #pragma unroll
    for (int h = 0; h < 2; ++h) {
        const int rl  = wave * 32 + h * 16 + rowIn;
        const int c16 = slot ^ ((rl >> 1) & 3);
        ra[h] = *(const int4*)(N + (size_t)(i0 + rl) * D_SZ + k0 + c16 * 16);
        rb[h] = *(const int4*)(N + (size_t)(j0 + rl) * D_SZ + k0 + c16 * 16);
    }
}

// VGPR -> LDS (ds_write_b128), matching the r13 LDS layout.
__device__ __forceinline__ void store_stage(const int4 ra[2], const int4 rb[2],
                                            unsigned char* bA, unsigned char* bB,
                                            int wave, int lane) {
    const int rowIn = lane >> 2, slot = lane & 3;
    #pragma unroll
    for (int h = 0; h < 2; ++h) {
        const int rl = wave * 32 + h * 16 + rowIn;
        *(int4*)&bA[rl * 64 + slot * 16] = ra[h];
        *(int4*)&bB[rl * 64 + slot * 16] = rb[h];
    }
}

// ---------------- fused sim: fp8 VGPR-staged pipeline, persistent ----------
// Per stage: ds_write(regs k) [waits aged vmcnt] -> issue loads k+1 ->
// __syncthreads [lgkm only -- loads stay IN FLIGHT across the barrier] ->
// ds_read + MFMA fp8. Dbuf LDS 32 KB -> 4 blocks/CU (2x r17 residency).
__global__ __launch_bounds__(256) void sim_kernel(const unsigned char* __restrict__ N,
                                                  const int* __restrict__ ids,
                                                  float* __restrict__ all_sum,
                                                  float* __restrict__ pos_sum) {
    __shared__ __align__(16) unsigned char smem[32768];   // A0|B0|A1|B1, 8 KB each

    const int t    = threadIdx.x;
    const int wave = t >> 6, lane = t & 63;
    const int wy   = wave >> 1, wx = wave & 1;
    const int myc  = lane & 15;

    int tb = blockIdx.x;
    int i0, j0; bool diag;
    decode_tile(tb, i0, j0, diag);

    int4 ra[2], rb[2];
    load_regs(ra, rb, N, i0, j0, 0, wave, lane);

    while (true) {
        const int ntb = tb + GRID_SIM;
        const bool have_next = (ntb < NTILES);
        int ni0 = i0, nj0 = j0; bool ndiag = diag;
        if (have_next) decode_tile(ntb, ni0, nj0, ndiag);

        f32x4 acc[4][4];
        #pragma unroll
        for (int mi = 0; mi < 4; ++mi)
            #pragma unroll
            for (int ni = 0; ni < 4; ++ni)
                acc[mi][ni] = (f32x4){0.f, 0.f, 0.f, 0.f};

        #pragma unroll
        for (int kk = 0; kk < 4; ++kk) {
            unsigned char* bA = smem + (kk & 1) * 16384;
            unsigned char* bB = bA + 8192;
            store_stage(ra, rb, bA, bB, wave, lane);
            if (kk < 3)           load_regs(ra, rb, N, i0, j0, (kk + 1) * 64, wave, lane);
            else if (have_next)   load_regs(ra, rb, N, ni0, nj0, 0, wave, lane);
            __syncthreads();      // lgkm drain; new global loads stay in flight

            #pragma unroll
            for (int ks = 0; ks < 2; ++ks) {
                const int C8 = ks * 4 + (lane >> 4);   // 8B chunk 0..7
                const int hi = C8 >> 1, lo = (C8 & 1) * 8;
                long long af[4], bf[4];
                #pragma unroll
                for (int mi = 0; mi < 4; ++mi) {
                    const int rr = wy * 64 + mi * 16 + (lane & 15);
                    af[mi] = *(const long long*)&bA[rr * 64 + (hi ^ ((rr >> 1) & 3)) * 16 + lo];
                }
                #pragma unroll
                for (int ni = 0; ni < 4; ++ni) {
                    const int rr = wx * 64 + ni * 16 + (lane & 15);
                    bf[ni] = *(const long long*)&bB[rr * 64 + (hi ^ ((rr >> 1) & 3)) * 16 + lo];
                }
                #pragma unroll
                for (int mi = 0; mi < 4; ++mi)
                    #pragma unroll
                    for (int ni = 0; ni < 4; ++ni)
                        acc[mi][ni] = __builtin_amdgcn_mfma_f32_16x16x32_fp8_fp8(
                            af[mi], bf[ni], acc[mi][ni], 0, 0, 0);
            }
            // WAR safety: buf (kk&1) rewritten at kk+2, after barrier kk+1.
        }
        __syncthreads();   // all buf1 reads done before rowPos overlays it

        // ---- epilogue (r11 logic).  C/D map: col=lane&15, row=(lane>>4)*4+reg
        float* rowAllPart = (float*)smem;             // [128][32] over A0|B0
        float* rowPosPart = (float*)(smem + 16384);   // [128][32] over A1|B1

        int idc[4];
        #pragma unroll
        for (int ni = 0; ni < 4; ++ni)
            idc[ni] = ids[j0 + wx * 64 + ni * 16 + myc];

        float cAll[4] = {0.f, 0.f, 0.f, 0.f};
        float cPos[4] = {0.f, 0.f, 0.f, 0.f};

        #pragma unroll
        for (int mi = 0; mi < 4; ++mi) {
            float rAll[4] = {0.f, 0.f, 0.f, 0.f};
            float rPos[4] = {0.f, 0.f, 0.f, 0.f};
            const int rbase = wy * 64 + mi * 16 + (lane >> 4) * 4;
            const int4 idr  = *(const int4*)&ids[i0 + rbase];
            #pragma unroll
            for (int ni = 0; ni < 4; ++ni) {
                const int cloc = wx * 64 + ni * 16 + myc;
                #pragma unroll
                for (int rg = 0; rg < 4; ++rg) {
                    const int lr = rbase + rg;
                    float e = __builtin_amdgcn_exp2f(acc[mi][ni][rg]);
                    if (diag && lr == cloc) e = 0.0f;        // diagonal element
                    rAll[rg] += e; cAll[ni] += e;
                    const int idrv = (rg == 0) ? idr.x : (rg == 1) ? idr.y
                                   : (rg == 2) ? idr.z : idr.w;
                    if (idrv == idc[ni]) { rPos[rg] += e; cPos[ni] += e; }
                }
            }
            #pragma unroll
            for (int rg = 0; rg < 4; ++rg) {
                rowAllPart[(rbase + rg) * 32 + wx * 16 + myc] = rAll[rg];
                rowPosPart[(rbase + rg) * 32 + wx * 16 + myc] = rPos[rg];
            }
        }

        // column sums -> rows j (off-diagonal tiles only; symmetry)
        if (!diag) {
            #pragma unroll
            for (int ni = 0; ni < 4; ++ni) {
                cAll[ni] += __shfl_xor(cAll[ni], 16, 64);
                cAll[ni] += __shfl_xor(cAll[ni], 32, 64);
                cPos[ni] += __shfl_xor(cPos[ni], 16, 64);
                cPos[ni] += __shfl_xor(cPos[ni], 32, 64);
            }
            if (lane < 16) {
                #pragma unroll
                for (int ni = 0; ni < 4; ++ni) {
                    const int gc = j0 + wx * 64 + ni * 16 + lane;
                    atomicAdd(&all_sum[gc], cAll[ni]);
                    if (cPos[ni] != 0.0f) atomicAdd(&pos_sum[gc], cPos[ni]);
                }
            }
        }

        __syncthreads();
        // row partial reduce: thread t -> (row = t&127, array = t>>7)
        {
            const int row = t & 127;
            const float* src = (t >= 128) ? rowPosPart : rowAllPart;
            float s = 0.0f;
            #pragma unroll
            for (int k8 = 0; k8 < 8; ++k8) {
                const int chunk = (k8 + (row & 7)) & 7;
                const float4 v = *(const float4*)&src[row * 32 + chunk * 4];
                s += v.x + v.y + v.z + v.w;
            }
            float* dst = (t >= 128) ? pos_sum : all_sum;
            atomicAdd(&dst[i0 + row], s);
        }
        __syncthreads();   // partials consumed; buffers reusable next tile

        if (!have_next) break;
        tb = ntb; i0 = ni0; j0 = nj0; diag = ndiag;
    }
}

// ---------------- final scalar reduce ----------------
__global__ __launch_bounds__(256) void loss_kernel(const float* __restrict__ all_sum,
                                                   const float* __restrict__ pos_sum,
                                                   float* __restrict__ out) {
    float loss = 0.0f, cnt = 0.0f;
    for (int i = threadIdx.x; i < B_SZ; i += 256) {
        float p = pos_sum[i], a = all_sum[i];
        if (p > 0.0f) { loss += logf(a) - logf(p); cnt += 1.0f; }
    }
    #pragma unroll
    for (int m = 1; m < 64; m <<= 1) {
        loss += __shfl_xor(loss, m, 64);
        cnt  += __shfl_xor(cnt, m, 64);
    }
    __shared__ float sl[4], sc[4];
    int wave = threadIdx.x >> 6, lane = threadIdx.x & 63;
    if (lane == 0) { sl[wave] = loss; sc[wave] = cnt; }
    __syncthreads();
    if (threadIdx.x == 0) {
        float L = sl[0] + sl[1] + sl[2] + sl[3];
        float C = sc[0] + sc[1] + sc[2] + sc[3];
        out[0] = L / fmaxf(C, 1.0f);
    }
}

extern "C" void kernel_launch(void* const* d_in, const int* in_sizes, int n_in,
                              void* d_out, int out_size, void* d_ws, size_t ws_size,
                              hipStream_t stream) {
    const float* emb = (const float*)d_in[0];
    const int*   ids = (const int*)d_in[1];
    float*       out = (float*)d_out;

    float*         all_sum = (float*)d_ws;
    float*         pos_sum = all_sum + B_SZ;
    unsigned char* nq      = (unsigned char*)d_ws + 65536;   // 8192*256 fp8 = 2 MB

    norm_kernel<<<256, 256, 0, stream>>>(emb, nq, all_sum);
    sim_kernel<<<GRID_SIM, 256, 0, stream>>>(nq, ids, all_sum, pos_sum);
    loss_kernel<<<1, 256, 0, stream>>>(all_sum, pos_sum, out);
}